// Round 7
// baseline (1148.690 us; speedup 1.0000x reference)
//
#include <hip/hip_runtime.h>
#include <hip/hip_bf16.h>
#include <math.h>

#define NPIX 196608
#define SCALE_Q 0.17677669529663687f

typedef __attribute__((ext_vector_type(4))) float f32x4;
typedef __attribute__((ext_vector_type(8))) short short8;
typedef __attribute__((ext_vector_type(4))) short short4v;
typedef __hip_bfloat16 bf16;

__device__ __forceinline__ float gelu_f(float x) {
    float yy = 1.5957691216057308f * (x + 0.044715f * x * x * x);
    float e = __expf(yy);
    return x - x * __builtin_amdgcn_rcpf(e + 1.0f);
}

__device__ __forceinline__ short bfbits(float f) {
    bf16 h = __float2bfloat16(f);
    return *reinterpret_cast<short*>(&h);
}

__device__ __forceinline__ short8 gld8(const bf16* p) {
    return *reinterpret_cast<const short8*>(p);
}

// ---------------- weight convert to bf16 transposed images (all linear) ---
__global__ __launch_bounds__(256) void k_convert(
    const float* __restrict__ wff1, const float* __restrict__ wqkv,
    const float* __restrict__ wproj, const float* __restrict__ wmlp1,
    const float* __restrict__ wmlp2, const float* __restrict__ wff2,
    bf16* __restrict__ dst)
{
    int gid = blockIdx.x * 256 + threadIdx.x;
    if (gid < 8192) {                       // ff1t [128 n][64 k]
        int n = gid >> 6, k = gid & 63;
        dst[gid] = __float2bfloat16(wff1[k * 128 + n]);
    } else if (gid < 106496) {              // qkvt [l][384 n][128 k]
        int r = gid - 8192; int l = r / 49152; r -= l * 49152;
        int n = r >> 7, k = r & 127;
        dst[gid] = __float2bfloat16(wqkv[l * 49152 + k * 384 + n]);
    } else if (gid < 139264) {              // projt [l][128 n][128 k]
        int r = gid - 106496; int l = r / 16384; r -= l * 16384;
        int n = r >> 7, k = r & 127;
        dst[gid] = __float2bfloat16(wproj[l * 16384 + k * 128 + n]);
    } else if (gid < 270336) {              // mlp1t [l][512 n][128 k]
        int r = gid - 139264; int l = r >> 16; r &= 65535;
        int n = r >> 7, k = r & 127;
        dst[gid] = __float2bfloat16(wmlp1[l * 65536 + k * 512 + n]);
    } else if (gid < 401408) {              // mlp2t [l][128 n][512 k]
        int r = gid - 270336; int l = r >> 16; r &= 65535;
        int n = r >> 9, k = r & 511;
        dst[gid] = __float2bfloat16(wmlp2[l * 65536 + k * 128 + n]);
    } else if (gid < 409600) {              // ff2t [64 n][128 k]
        int r = gid - 401408;
        int n = r >> 7, k = r & 127;
        dst[gid] = __float2bfloat16(wff2[k * 64 + n]);
    }
}

// ---------------- one wave = one 16-token window = whole block (no barriers)
// MODE 0: ff1 fused at head (reads x), writes h at tail.
// MODE 1: reads h at head, ff2 fused at tail (writes out).
template <int OFFSET, int MODE>
__global__ __launch_bounds__(64, 2) void k_block(
    const float* __restrict__ x, float* __restrict__ h,
    const bf16* __restrict__ wf1t, const float* __restrict__ bf1,
    const float* __restrict__ g1, const float* __restrict__ be1,
    const bf16* __restrict__ wqt, const float* __restrict__ bq,
    const bf16* __restrict__ wpt, const float* __restrict__ bp,
    const float* __restrict__ g2, const float* __restrict__ be2,
    const bf16* __restrict__ w1t, const float* __restrict__ b1,
    const bf16* __restrict__ w2t, const float* __restrict__ b2,
    const bf16* __restrict__ wf2t, const float* __restrict__ bf2,
    float* __restrict__ out)
{
    __shared__ __align__(16) bf16 S[8192];          // 16 KB, 4 phase-reused regions
    bf16* XN1 = S;           // [16][128] xn1 -> attn-out
    bf16* QQ  = S + 2048;    // [16][128] q -> P(first 1024) -> xn2
    bf16* KK  = S + 4096;    // xs(MODE0) -> k -> u(ch even) -> hfinal(MODE1)
    bf16* VT  = S + 6144;    // [128 d][16 key] vt -> u(ch odd)
    const int lane = threadIdx.x;
    const int lrow = lane & 15, lgrp = lane >> 4;
    const int base = blockIdx.x * 16;
    int tok = base + OFFSET + lrow; if (tok >= NPIX) tok -= NPIX;
    const int sw = (lrow & 7) << 3;

    f32x4 hraw[8];     // h residual, [nt]: lane n = nt*16+lgrp*4+i, token = lrow

    if (MODE == 0) {
        // ---- ff1 fused: stage x (bf16, swizzled 64-wide) into KK
        const float4* src = reinterpret_cast<const float4*>(x + (size_t)(base + lrow) * 64 + lgrp * 16);
        float4 v0 = src[0], v1 = src[1], v2 = src[2], v3 = src[3];
        short8 w0, w1;
        w0[0]=bfbits(v0.x); w0[1]=bfbits(v0.y); w0[2]=bfbits(v0.z); w0[3]=bfbits(v0.w);
        w0[4]=bfbits(v1.x); w0[5]=bfbits(v1.y); w0[6]=bfbits(v1.z); w0[7]=bfbits(v1.w);
        w1[0]=bfbits(v2.x); w1[1]=bfbits(v2.y); w1[2]=bfbits(v2.z); w1[3]=bfbits(v2.w);
        w1[4]=bfbits(v3.x); w1[5]=bfbits(v3.y); w1[6]=bfbits(v3.z); w1[7]=bfbits(v3.w);
        *reinterpret_cast<short8*>(&KK[lrow * 64 + ((lgrp * 16) ^ sw)]) = w0;
        *reinterpret_cast<short8*>(&KK[lrow * 64 + ((lgrp * 16 + 8) ^ sw)]) = w1;
        short8 xb1[2];
#pragma unroll
        for (int kk = 0; kk < 2; ++kk)
            xb1[kk] = *reinterpret_cast<const short8*>(&KK[lrow * 64 + ((kk * 32 + lgrp * 8) ^ sw)]);
#pragma unroll
        for (int nt = 0; nt < 8; ++nt) {
            short8 wf[2];
#pragma unroll
            for (int kk = 0; kk < 2; ++kk)
                wf[kk] = gld8(wf1t + (size_t)(nt * 16 + lrow) * 64 + kk * 32 + lgrp * 8);
            f32x4 d = {0.f, 0.f, 0.f, 0.f};
#pragma unroll
            for (int kk = 0; kk < 2; ++kk)
                d = __builtin_amdgcn_mfma_f32_16x16x32_bf16(wf[kk], xb1[kk], d, 0, 0, 0);
            float4 bv = *reinterpret_cast<const float4*>(bf1 + nt * 16 + lgrp * 4);
            f32x4 r;
            r[0] = gelu_f(d[0] + bv.x); r[1] = gelu_f(d[1] + bv.y);
            r[2] = gelu_f(d[2] + bv.z); r[3] = gelu_f(d[3] + bv.w);
            hraw[nt] = r;
        }
    } else {
#pragma unroll
        for (int nt = 0; nt < 8; ++nt) {
            float4 hv = *reinterpret_cast<const float4*>(h + (size_t)tok * 128 + nt * 16 + lgrp * 4);
            f32x4 r; r[0] = hv.x; r[1] = hv.y; r[2] = hv.z; r[3] = hv.w;
            hraw[nt] = r;
        }
    }

    // ---- LN1 (intra-wave: reduce over n across lgrp) -> xn1
    {
        float s = 0.f, q = 0.f;
#pragma unroll
        for (int nt = 0; nt < 8; ++nt)
#pragma unroll
            for (int i = 0; i < 4; ++i) { float v = hraw[nt][i]; s += v; q += v * v; }
        s += __shfl_xor(s, 16, 64); s += __shfl_xor(s, 32, 64);
        q += __shfl_xor(q, 16, 64); q += __shfl_xor(q, 32, 64);
        float mu = s * (1.f / 128.f);
        float rstd = rsqrtf(q * (1.f / 128.f) - mu * mu + 1e-5f);
#pragma unroll
        for (int nt = 0; nt < 8; ++nt) {
            float4 gv  = *reinterpret_cast<const float4*>(g1 + nt * 16 + lgrp * 4);
            float4 bev = *reinterpret_cast<const float4*>(be1 + nt * 16 + lgrp * 4);
            short4v pk;
            pk[0] = bfbits((hraw[nt][0] - mu) * rstd * gv.x + bev.x);
            pk[1] = bfbits((hraw[nt][1] - mu) * rstd * gv.y + bev.y);
            pk[2] = bfbits((hraw[nt][2] - mu) * rstd * gv.z + bev.z);
            pk[3] = bfbits((hraw[nt][3] - mu) * rstd * gv.w + bev.w);
            *reinterpret_cast<short4v*>(&XN1[lrow * 128 + ((nt * 16 + lgrp * 4) ^ sw)]) = pk;
        }
    }
    short8 xb[4];   // xn1 fragments: serve as B-frag (n=tok) AND A-frag (m=tok)
#pragma unroll
    for (int kk = 0; kk < 4; ++kk)
        xb[kk] = *reinterpret_cast<const short8*>(&XN1[lrow * 128 + ((kk * 32 + lgrp * 8) ^ sw)]);

    // ---- q tiles (D[qcol][tok], store [tok][qcol])
#pragma unroll
    for (int nt = 0; nt < 8; ++nt) {
        short8 wf[4];
#pragma unroll
        for (int kk = 0; kk < 4; ++kk)
            wf[kk] = gld8(wqt + (size_t)(nt * 16 + lrow) * 128 + kk * 32 + lgrp * 8);
        f32x4 d = {0.f, 0.f, 0.f, 0.f};
#pragma unroll
        for (int kk = 0; kk < 4; ++kk)
            d = __builtin_amdgcn_mfma_f32_16x16x32_bf16(wf[kk], xb[kk], d, 0, 0, 0);
        float4 bv = *reinterpret_cast<const float4*>(bq + nt * 16 + lgrp * 4);
        short4v pk;
        pk[0] = bfbits((d[0] + bv.x) * SCALE_Q); pk[1] = bfbits((d[1] + bv.y) * SCALE_Q);
        pk[2] = bfbits((d[2] + bv.z) * SCALE_Q); pk[3] = bfbits((d[3] + bv.w) * SCALE_Q);
        *reinterpret_cast<short4v*>(&QQ[lrow * 128 + ((nt * 16 + lgrp * 4) ^ sw)]) = pk;
    }
    // ---- k tiles
#pragma unroll
    for (int nt = 0; nt < 8; ++nt) {
        short8 wf[4];
#pragma unroll
        for (int kk = 0; kk < 4; ++kk)
            wf[kk] = gld8(wqt + (size_t)(128 + nt * 16 + lrow) * 128 + kk * 32 + lgrp * 8);
        f32x4 d = {0.f, 0.f, 0.f, 0.f};
#pragma unroll
        for (int kk = 0; kk < 4; ++kk)
            d = __builtin_amdgcn_mfma_f32_16x16x32_bf16(wf[kk], xb[kk], d, 0, 0, 0);
        float4 bv = *reinterpret_cast<const float4*>(bq + 128 + nt * 16 + lgrp * 4);
        short4v pk;
        pk[0] = bfbits(d[0] + bv.x); pk[1] = bfbits(d[1] + bv.y);
        pk[2] = bfbits(d[2] + bv.z); pk[3] = bfbits(d[3] + bv.w);
        *reinterpret_cast<short4v*>(&KK[lrow * 128 + ((nt * 16 + lgrp * 4) ^ sw)]) = pk;
    }
    // ---- v tiles: A=xn (m=tok), B=wv -> D[tok][vcol]; store VT[d][key] contiguously
#pragma unroll
    for (int dt = 0; dt < 8; ++dt) {
        short8 wv[4];
#pragma unroll
        for (int kk = 0; kk < 4; ++kk)
            wv[kk] = gld8(wqt + (size_t)(256 + dt * 16 + lrow) * 128 + kk * 32 + lgrp * 8);
        f32x4 d = {0.f, 0.f, 0.f, 0.f};
#pragma unroll
        for (int kk = 0; kk < 4; ++kk)
            d = __builtin_amdgcn_mfma_f32_16x16x32_bf16(xb[kk], wv[kk], d, 0, 0, 0);
        float bv = bq[256 + dt * 16 + lrow];    // per-vcol bias (lane-varying)
        short4v pk;
        pk[0] = bfbits(d[0] + bv); pk[1] = bfbits(d[1] + bv);
        pk[2] = bfbits(d[2] + bv); pk[3] = bfbits(d[3] + bv);
        *reinterpret_cast<short4v*>(&VT[(dt * 16 + lrow) * 16 + lgrp * 4]) = pk;
    }

    // ---- scores + softmax (intra-wave shfl)
    float p[4][4];
#pragma unroll
    for (int hh = 0; hh < 4; ++hh) {
        short8 aq = *reinterpret_cast<const short8*>(&QQ[lrow * 128 + ((hh * 32 + lgrp * 8) ^ sw)]);
        short8 bk = *reinterpret_cast<const short8*>(&KK[lrow * 128 + ((hh * 32 + lgrp * 8) ^ sw)]);
        f32x4 z = {0.f, 0.f, 0.f, 0.f};
        f32x4 s = __builtin_amdgcn_mfma_f32_16x16x32_bf16(aq, bk, z, 0, 0, 0);
#pragma unroll
        for (int i = 0; i < 4; ++i) {
            float m_ = s[i];
            m_ = fmaxf(m_, __shfl_xor(m_, 1, 64));
            m_ = fmaxf(m_, __shfl_xor(m_, 2, 64));
            m_ = fmaxf(m_, __shfl_xor(m_, 4, 64));
            m_ = fmaxf(m_, __shfl_xor(m_, 8, 64));
            float e = __expf(s[i] - m_);
            float sum = e;
            sum += __shfl_xor(sum, 1, 64);
            sum += __shfl_xor(sum, 2, 64);
            sum += __shfl_xor(sum, 4, 64);
            sum += __shfl_xor(sum, 8, 64);
            p[hh][i] = e * __builtin_amdgcn_rcpf(sum);
        }
    }
    // P -> QQ[0..1023] (q fully consumed): pl[hh][tok_q][tok_k]
#pragma unroll
    for (int hh = 0; hh < 4; ++hh)
#pragma unroll
        for (int i = 0; i < 4; ++i)
            QQ[hh * 256 + (lgrp * 4 + i) * 16 + lrow] = __float2bfloat16(p[hh][i]);

    // ---- PV: D[d][tok]; keys 16..31 zero via zero regs; out -> XN1 (xn1 dead)
    short8 z8 = {0, 0, 0, 0, 0, 0, 0, 0};
#pragma unroll
    for (int dt = 0; dt < 8; ++dt) {
        int hh = dt >> 1;
        short8 av = z8, bv = z8;
        if (lgrp < 2) {
            av = *reinterpret_cast<const short8*>(&VT[(dt * 16 + lrow) * 16 + lgrp * 8]);
            bv = *reinterpret_cast<const short8*>(&QQ[hh * 256 + lrow * 16 + lgrp * 8]);
        }
        f32x4 z = {0.f, 0.f, 0.f, 0.f};
        f32x4 o = __builtin_amdgcn_mfma_f32_16x16x32_bf16(av, bv, z, 0, 0, 0);
        short4v pk;
        pk[0] = bfbits(o[0]); pk[1] = bfbits(o[1]); pk[2] = bfbits(o[2]); pk[3] = bfbits(o[3]);
        *reinterpret_cast<short4v*>(&XN1[lrow * 128 + ((dt * 16 + lgrp * 4) ^ sw)]) = pk;
    }

    // ---- proj + residual
    short8 af[4];
#pragma unroll
    for (int kk = 0; kk < 4; ++kk)
        af[kk] = *reinterpret_cast<const short8*>(&XN1[lrow * 128 + ((kk * 32 + lgrp * 8) ^ sw)]);
    f32x4 hres[8];
#pragma unroll
    for (int nt = 0; nt < 8; ++nt) {
        short8 wf[4];
#pragma unroll
        for (int kk = 0; kk < 4; ++kk)
            wf[kk] = gld8(wpt + (size_t)(nt * 16 + lrow) * 128 + kk * 32 + lgrp * 8);
        f32x4 d = {0.f, 0.f, 0.f, 0.f};
#pragma unroll
        for (int kk = 0; kk < 4; ++kk)
            d = __builtin_amdgcn_mfma_f32_16x16x32_bf16(wf[kk], af[kk], d, 0, 0, 0);
        float4 bv = *reinterpret_cast<const float4*>(bp + nt * 16 + lgrp * 4);
        f32x4 r = hraw[nt];
        r[0] += bv.x + d[0]; r[1] += bv.y + d[1];
        r[2] += bv.z + d[2]; r[3] += bv.w + d[3];
        hres[nt] = r;
    }

    // ---- LN2 -> xn2 in QQ (P dead)
    {
        float s = 0.f, q = 0.f;
#pragma unroll
        for (int nt = 0; nt < 8; ++nt)
#pragma unroll
            for (int i = 0; i < 4; ++i) { float v = hres[nt][i]; s += v; q += v * v; }
        s += __shfl_xor(s, 16, 64); s += __shfl_xor(s, 32, 64);
        q += __shfl_xor(q, 16, 64); q += __shfl_xor(q, 32, 64);
        float mu = s * (1.f / 128.f);
        float rstd = rsqrtf(q * (1.f / 128.f) - mu * mu + 1e-5f);
#pragma unroll
        for (int nt = 0; nt < 8; ++nt) {
            float4 gv  = *reinterpret_cast<const float4*>(g2 + nt * 16 + lgrp * 4);
            float4 bev = *reinterpret_cast<const float4*>(be2 + nt * 16 + lgrp * 4);
            short4v pk;
            pk[0] = bfbits((hres[nt][0] - mu) * rstd * gv.x + bev.x);
            pk[1] = bfbits((hres[nt][1] - mu) * rstd * gv.y + bev.y);
            pk[2] = bfbits((hres[nt][2] - mu) * rstd * gv.z + bev.z);
            pk[3] = bfbits((hres[nt][3] - mu) * rstd * gv.w + bev.w);
            *reinterpret_cast<short4v*>(&QQ[lrow * 128 + ((nt * 16 + lgrp * 4) ^ sw)]) = pk;
        }
    }
    short8 xb2[4];
#pragma unroll
    for (int kk = 0; kk < 4; ++kk)
        xb2[kk] = *reinterpret_cast<const short8*>(&QQ[lrow * 128 + ((kk * 32 + lgrp * 8) ^ sw)]);

    // ---- MLP: 4 chunks of 128; u ping-pongs KK/VT; no barriers
    f32x4 acc2[8];
#pragma unroll
    for (int nt = 0; nt < 8; ++nt) acc2[nt] = (f32x4){0.f, 0.f, 0.f, 0.f};
#pragma unroll
    for (int ch = 0; ch < 4; ++ch) {
        bf16* UB = (ch & 1) ? VT : KK;
#pragma unroll
        for (int nt = 0; nt < 8; ++nt) {
            short8 wf[4];
#pragma unroll
            for (int kk = 0; kk < 4; ++kk)
                wf[kk] = gld8(w1t + (size_t)(ch * 128 + nt * 16 + lrow) * 128 + kk * 32 + lgrp * 8);
            f32x4 d = {0.f, 0.f, 0.f, 0.f};
#pragma unroll
            for (int kk = 0; kk < 4; ++kk)
                d = __builtin_amdgcn_mfma_f32_16x16x32_bf16(wf[kk], xb2[kk], d, 0, 0, 0);
            float4 bv = *reinterpret_cast<const float4*>(b1 + ch * 128 + nt * 16 + lgrp * 4);
            short4v pk;
            pk[0] = bfbits(gelu_f(d[0] + bv.x)); pk[1] = bfbits(gelu_f(d[1] + bv.y));
            pk[2] = bfbits(gelu_f(d[2] + bv.z)); pk[3] = bfbits(gelu_f(d[3] + bv.w));
            *reinterpret_cast<short4v*>(&UB[lrow * 128 + ((nt * 16 + lgrp * 4) ^ sw)]) = pk;
        }
        short8 uf[4];
#pragma unroll
        for (int kk = 0; kk < 4; ++kk)
            uf[kk] = *reinterpret_cast<const short8*>(&UB[lrow * 128 + ((kk * 32 + lgrp * 8) ^ sw)]);
#pragma unroll
        for (int nt = 0; nt < 8; ++nt) {
            short8 wf[4];
#pragma unroll
            for (int kk = 0; kk < 4; ++kk)
                wf[kk] = gld8(w2t + (size_t)(nt * 16 + lrow) * 512 + ch * 128 + kk * 32 + lgrp * 8);
#pragma unroll
            for (int kk = 0; kk < 4; ++kk)
                acc2[nt] = __builtin_amdgcn_mfma_f32_16x16x32_bf16(wf[kk], uf[kk], acc2[nt], 0, 0, 0);
        }
    }

    if (MODE == 0) {
        // ---- epilogue: h = hres + b2 + acc2
#pragma unroll
        for (int nt = 0; nt < 8; ++nt) {
            float4 b2v = *reinterpret_cast<const float4*>(b2 + nt * 16 + lgrp * 4);
            float4 ov;
            ov.x = hres[nt][0] + b2v.x + acc2[nt][0];
            ov.y = hres[nt][1] + b2v.y + acc2[nt][1];
            ov.z = hres[nt][2] + b2v.z + acc2[nt][2];
            ov.w = hres[nt][3] + b2v.w + acc2[nt][3];
            *reinterpret_cast<float4*>(h + (size_t)tok * 128 + nt * 16 + lgrp * 4) = ov;
        }
    } else {
        // ---- epilogue: hfinal -> KK -> ff2 -> out = x + hf @ wff2 + bff2
#pragma unroll
        for (int nt = 0; nt < 8; ++nt) {
            float4 b2v = *reinterpret_cast<const float4*>(b2 + nt * 16 + lgrp * 4);
            short4v pk;
            pk[0] = bfbits(hres[nt][0] + b2v.x + acc2[nt][0]);
            pk[1] = bfbits(hres[nt][1] + b2v.y + acc2[nt][1]);
            pk[2] = bfbits(hres[nt][2] + b2v.z + acc2[nt][2]);
            pk[3] = bfbits(hres[nt][3] + b2v.w + acc2[nt][3]);
            *reinterpret_cast<short4v*>(&KK[lrow * 128 + ((nt * 16 + lgrp * 4) ^ sw)]) = pk;
        }
        short8 bfr[4];
#pragma unroll
        for (int kk = 0; kk < 4; ++kk)
            bfr[kk] = *reinterpret_cast<const short8*>(&KK[lrow * 128 + ((kk * 32 + lgrp * 8) ^ sw)]);
#pragma unroll
        for (int nt = 0; nt < 4; ++nt) {
            short8 wf[4];
#pragma unroll
            for (int kk = 0; kk < 4; ++kk)
                wf[kk] = gld8(wf2t + (size_t)(nt * 16 + lrow) * 128 + kk * 32 + lgrp * 8);
            f32x4 d = {0.f, 0.f, 0.f, 0.f};
#pragma unroll
            for (int kk = 0; kk < 4; ++kk)
                d = __builtin_amdgcn_mfma_f32_16x16x32_bf16(wf[kk], bfr[kk], d, 0, 0, 0);
            float4 bv = *reinterpret_cast<const float4*>(bf2 + nt * 16 + lgrp * 4);
            size_t gidx = (size_t)tok * 64 + nt * 16 + lgrp * 4;
            float4 xv = *reinterpret_cast<const float4*>(x + gidx);
            float4 ov;
            ov.x = xv.x + bv.x + d[0]; ov.y = xv.y + bv.y + d[1];
            ov.z = xv.z + bv.z + d[2]; ov.w = xv.w + bv.w + d[3];
            *reinterpret_cast<float4*>(out + gidx) = ov;
        }
    }
}

extern "C" void kernel_launch(void* const* d_in, const int* in_sizes, int n_in,
                              void* d_out, int out_size, void* d_ws, size_t ws_size,
                              hipStream_t stream) {
    (void)in_sizes; (void)n_in; (void)out_size; (void)ws_size;
    const float* x      = (const float*)d_in[0];
    const float* w_ff1  = (const float*)d_in[1];
    const float* b_ff1  = (const float*)d_in[2];
    const float* ln1_g  = (const float*)d_in[3];
    const float* ln1_b  = (const float*)d_in[4];
    const float* w_qkv  = (const float*)d_in[5];
    const float* b_qkv  = (const float*)d_in[6];
    const float* w_proj = (const float*)d_in[7];
    const float* b_proj = (const float*)d_in[8];
    const float* ln2_g  = (const float*)d_in[9];
    const float* ln2_b  = (const float*)d_in[10];
    const float* w_mlp1 = (const float*)d_in[11];
    const float* b_mlp1 = (const float*)d_in[12];
    const float* w_mlp2 = (const float*)d_in[13];
    const float* b_mlp2 = (const float*)d_in[14];
    const float* w_ff2  = (const float*)d_in[15];
    const float* b_ff2  = (const float*)d_in[16];
    float* out = (float*)d_out;

    float* h = (float*)d_ws;                                   // [NPIX,128] fp32
    bf16* wbf = (bf16*)((char*)d_ws + (size_t)NPIX * 128 * 4);
    bf16* ff1t  = wbf;            // [128][64]
    bf16* qkvt  = wbf + 8192;     // 2x[384][128]
    bf16* projt = wbf + 106496;   // 2x[128][128]
    bf16* mlp1t = wbf + 139264;   // 2x[512][128]
    bf16* mlp2t = wbf + 270336;   // 2x[128][512]
    bf16* ff2t  = wbf + 401408;   // [64][128]

    k_convert<<<1600, dim3(256), 0, stream>>>(w_ff1, w_qkv, w_proj, w_mlp1, w_mlp2, w_ff2, wbf);

    const int NB = NPIX / 16;  // 12288 blocks, 1 wave each
    k_block<0, 0><<<NB, dim3(64), 0, stream>>>(x, h,
        ff1t, b_ff1,
        ln1_g, ln1_b, qkvt, b_qkv, projt, b_proj,
        ln2_g, ln2_b, mlp1t, b_mlp1, mlp2t, b_mlp2,
        ff2t, b_ff2, out);

    k_block<8, 1><<<NB, dim3(64), 0, stream>>>(x, h,
        ff1t, b_ff1,
        ln1_g + 128, ln1_b + 128, qkvt + 49152, b_qkv + 384, projt + 16384, b_proj + 128,
        ln2_g + 128, ln2_b + 128, mlp1t + 65536, b_mlp1 + 512, mlp2t + 65536, b_mlp2 + 128,
        ff2t, b_ff2, out);
}

// Round 8
// 542.357 us; speedup vs baseline: 2.1180x; 2.1180x over previous
//
#include <hip/hip_runtime.h>
#include <hip/hip_bf16.h>
#include <math.h>

#define NPIX 196608
#define SCALE_Q 0.17677669529663687f

typedef __attribute__((ext_vector_type(4))) float f32x4;
typedef __attribute__((ext_vector_type(8))) short short8;
typedef __attribute__((ext_vector_type(4))) short short4v;
typedef __hip_bfloat16 bf16;

__device__ __forceinline__ float gelu_f(float x) {
    float yy = 1.5957691216057308f * (x + 0.044715f * x * x * x);
    float e = __expf(yy);
    return x - x * __builtin_amdgcn_rcpf(e + 1.0f);
}

__device__ __forceinline__ short bfbits(float f) {
    bf16 h = __float2bfloat16(f);
    return *reinterpret_cast<short*>(&h);
}

__device__ __forceinline__ short8 ldsA(const bf16* buf, int row, int el) {
    return *reinterpret_cast<const short8*>(buf + row * 128 + (el ^ ((row & 7) << 3)));
}
__device__ __forceinline__ short8 ldsA64(const bf16* buf, int row, int el) {
    return *reinterpret_cast<const short8*>(buf + row * 64 + (el ^ ((row & 7) << 3)));
}
__device__ __forceinline__ short8 gld8(const bf16* p) {
    return *reinterpret_cast<const short8*>(p);
}

// LDS-only barrier: drains ds ops, does NOT drain vmcnt -> register prefetches
// (weights) stay in flight across phases. (m194-m204 verified pattern.)
__device__ __forceinline__ void bar_lds() {
    __builtin_amdgcn_sched_barrier(0);
    asm volatile("s_waitcnt lgkmcnt(0)" ::: "memory");
    __builtin_amdgcn_s_barrier();
    __builtin_amdgcn_sched_barrier(0);
}

// ---------------- weight convert to bf16 transposed images (all linear) ---
__global__ __launch_bounds__(256) void k_convert(
    const float* __restrict__ wff1, const float* __restrict__ wqkv,
    const float* __restrict__ wproj, const float* __restrict__ wmlp1,
    const float* __restrict__ wmlp2, const float* __restrict__ wff2,
    bf16* __restrict__ dst)
{
    int gid = blockIdx.x * 256 + threadIdx.x;
    if (gid < 8192) {                       // ff1t [128 n][64 k]
        int n = gid >> 6, k = gid & 63;
        dst[gid] = __float2bfloat16(wff1[k * 128 + n]);
    } else if (gid < 106496) {              // qkvt [l][384 n][128 k]
        int r = gid - 8192; int l = r / 49152; r -= l * 49152;
        int n = r >> 7, k = r & 127;
        dst[gid] = __float2bfloat16(wqkv[l * 49152 + k * 384 + n]);
    } else if (gid < 139264) {              // projt [l][128 n][128 k]
        int r = gid - 106496; int l = r / 16384; r -= l * 16384;
        int n = r >> 7, k = r & 127;
        dst[gid] = __float2bfloat16(wproj[l * 16384 + k * 128 + n]);
    } else if (gid < 270336) {              // mlp1t [l][512 n][128 k]
        int r = gid - 139264; int l = r >> 16; r &= 65535;
        int n = r >> 7, k = r & 127;
        dst[gid] = __float2bfloat16(wmlp1[l * 65536 + k * 512 + n]);
    } else if (gid < 401408) {              // mlp2t [l][128 n][512 k]
        int r = gid - 270336; int l = r >> 16; r &= 65535;
        int n = r >> 9, k = r & 511;
        dst[gid] = __float2bfloat16(wmlp2[l * 65536 + k * 128 + n]);
    } else if (gid < 409600) {              // ff2t [64 n][128 k]
        int r = gid - 401408;
        int n = r >> 7, k = r & 127;
        dst[gid] = __float2bfloat16(wff2[k * 64 + n]);
    }
}

// ---------------- fused block kernel ------------------------------------
// MODE 0: ff1 fused at head (reads x), writes h at tail.
// MODE 1: reads h at head, ff2 fused at tail (writes out).
template <int OFFSET, int MODE>
__global__ __launch_bounds__(256, 3) void k_block(
    const float* __restrict__ x, float* __restrict__ h,
    const bf16* __restrict__ wf1t, const float* __restrict__ bf1,
    const float* __restrict__ g1, const float* __restrict__ be1,
    const bf16* __restrict__ wqt, const float* __restrict__ bq,
    const bf16* __restrict__ wpt, const float* __restrict__ bp,
    const float* __restrict__ g2, const float* __restrict__ be2,
    const bf16* __restrict__ w1t, const float* __restrict__ b1,
    const bf16* __restrict__ w2t, const float* __restrict__ b2,
    const bf16* __restrict__ wf2t, const float* __restrict__ bf2,
    float* __restrict__ out)
{
    __shared__ __align__(16) bf16 bufA[8192];  // xn1 -> q -> attn-out -> u(even)
    __shared__ __align__(16) bf16 bufB[8192];  // k/P -> xn2 -> hfinal(M1)
    __shared__ __align__(16) bf16 bufC[8192];  // xs(M0) / LN partials / vt -> u(odd)
    const int tid = threadIdx.x, base = blockIdx.x * 64;
    const int wid = tid >> 6, lrow = tid & 15, lgrp = (tid >> 4) & 3;
    const int cb0 = wid * 32;                  // wave's n-col base (128-dim data)

    f32x4 hraw[2][4];   // h residual: [nt][tt], n = cb0+nt*16+lgrp*4+i, token tt*16+lrow

    if (MODE == 0) {
        // ---- ff1 fused: stage x, prefetch ff1 frags, compute hraw = gelu(x@w+b)
        short8 wf1[2][2];
#pragma unroll
        for (int nt = 0; nt < 2; ++nt)
#pragma unroll
            for (int kk = 0; kk < 2; ++kk)
                wf1[nt][kk] = gld8(wf1t + (size_t)(cb0 + nt * 16 + lrow) * 64 + kk * 32 + lgrp * 8);
        {
            int row = tid >> 2, q = tid & 3;
#pragma unroll
            for (int s = 0; s < 2; ++s) {
                int gg = q + s * 4;
                const float4* src = reinterpret_cast<const float4*>(x + (size_t)(base + row) * 64 + gg * 8);
                float4 v0 = src[0], v1 = src[1];
                short8 w;
                w[0] = bfbits(v0.x); w[1] = bfbits(v0.y); w[2] = bfbits(v0.z); w[3] = bfbits(v0.w);
                w[4] = bfbits(v1.x); w[5] = bfbits(v1.y); w[6] = bfbits(v1.z); w[7] = bfbits(v1.w);
                *reinterpret_cast<short8*>(&bufC[row * 64 + ((gg * 8) ^ ((row & 7) << 3))]) = w;
            }
        }
        bar_lds();
        short8 xb1[4][2];
#pragma unroll
        for (int tt = 0; tt < 4; ++tt)
#pragma unroll
            for (int kk = 0; kk < 2; ++kk)
                xb1[tt][kk] = ldsA64(bufC, tt * 16 + lrow, kk * 32 + lgrp * 8);
        bar_lds();   // xs reads done; bufC reusable for LN partials
#pragma unroll
        for (int nt = 0; nt < 2; ++nt) {
            float4 bv = *reinterpret_cast<const float4*>(bf1 + cb0 + nt * 16 + lgrp * 4);
#pragma unroll
            for (int tt = 0; tt < 4; ++tt) {
                f32x4 d = {0.f, 0.f, 0.f, 0.f};
#pragma unroll
                for (int kk = 0; kk < 2; ++kk)
                    d = __builtin_amdgcn_mfma_f32_16x16x32_bf16(wf1[nt][kk], xb1[tt][kk], d, 0, 0, 0);
                f32x4 r;
                r[0] = gelu_f(d[0] + bv.x); r[1] = gelu_f(d[1] + bv.y);
                r[2] = gelu_f(d[2] + bv.z); r[3] = gelu_f(d[3] + bv.w);
                hraw[nt][tt] = r;
            }
        }
    } else {
        // ---- load h once, [n][token] register layout
#pragma unroll
        for (int nt = 0; nt < 2; ++nt)
#pragma unroll
            for (int tt = 0; tt < 4; ++tt) {
                int tok = base + OFFSET + tt * 16 + lrow; if (tok >= NPIX) tok -= NPIX;
                float4 hv = *reinterpret_cast<const float4*>(h + (size_t)tok * 128 + cb0 + nt * 16 + lgrp * 4);
                f32x4 r; r[0] = hv.x; r[1] = hv.y; r[2] = hv.z; r[3] = hv.w;
                hraw[nt][tt] = r;
            }
    }

    // ---- LN1 (cross-wave over n) -> xn1 in bufA
    float2* ws = reinterpret_cast<float2*>(bufC);
#pragma unroll
    for (int tt = 0; tt < 4; ++tt) {
        float s = 0.f, q = 0.f;
#pragma unroll
        for (int nt = 0; nt < 2; ++nt)
#pragma unroll
            for (int i = 0; i < 4; ++i) { float v = hraw[nt][tt][i]; s += v; q += v * v; }
        s += __shfl_xor(s, 16, 64); s += __shfl_xor(s, 32, 64);
        q += __shfl_xor(q, 16, 64); q += __shfl_xor(q, 32, 64);
        if (lgrp == 0) { float2 t2; t2.x = s; t2.y = q; ws[wid * 64 + tt * 16 + lrow] = t2; }
    }
    bar_lds();
    {
        float mu[4], rstd[4];
#pragma unroll
        for (int tt = 0; tt < 4; ++tt) {
            float s = 0.f, q = 0.f;
#pragma unroll
            for (int w = 0; w < 4; ++w) {
                float2 t2 = ws[w * 64 + tt * 16 + lrow];
                s += t2.x; q += t2.y;
            }
            float m = s * (1.f / 128.f);
            mu[tt] = m;
            rstd[tt] = rsqrtf(q * (1.f / 128.f) - m * m + 1e-5f);
        }
        float4 gv[2], bev[2];
#pragma unroll
        for (int nt = 0; nt < 2; ++nt) {
            gv[nt]  = *reinterpret_cast<const float4*>(g1 + cb0 + nt * 16 + lgrp * 4);
            bev[nt] = *reinterpret_cast<const float4*>(be1 + cb0 + nt * 16 + lgrp * 4);
        }
#pragma unroll
        for (int nt = 0; nt < 2; ++nt)
#pragma unroll
            for (int tt = 0; tt < 4; ++tt) {
                short4v pk;
                pk[0] = bfbits((hraw[nt][tt][0] - mu[tt]) * rstd[tt] * gv[nt].x + bev[nt].x);
                pk[1] = bfbits((hraw[nt][tt][1] - mu[tt]) * rstd[tt] * gv[nt].y + bev[nt].y);
                pk[2] = bfbits((hraw[nt][tt][2] - mu[tt]) * rstd[tt] * gv[nt].z + bev[nt].z);
                pk[3] = bfbits((hraw[nt][tt][3] - mu[tt]) * rstd[tt] * gv[nt].w + bev[nt].w);
                int row = tt * 16 + lrow;
                int c = cb0 + nt * 16 + lgrp * 4;
                *reinterpret_cast<short4v*>(&bufA[row * 128 + (c ^ ((row & 7) << 3))]) = pk;
            }
    }

    // prefetch qkv weight group 0 (nt 0,1) — stays in flight across barriers
    const int qc = wid * 96;
    short8 wq0[2][4], wq1[2][4];
#pragma unroll
    for (int j = 0; j < 2; ++j)
#pragma unroll
        for (int kk = 0; kk < 4; ++kk)
            wq0[j][kk] = gld8(wqt + (size_t)(qc + j * 16 + lrow) * 128 + kk * 32 + lgrp * 8);
    bar_lds();

    short8 xb[4][4];
#pragma unroll
    for (int tt = 0; tt < 4; ++tt)
#pragma unroll
        for (int kk = 0; kk < 4; ++kk)
            xb[tt][kk] = ldsA(bufA, tt * 16 + lrow, kk * 32 + lgrp * 8);
    bar_lds();   // xn1 reads done before q overwrites bufA

    // ---- qkv: 3 rolling groups of 2 n-tiles
#define QKV_TILE(WF, NB)                                                            \
    {                                                                               \
        const int cb = qc + (NB) * 16;                                              \
        float4 bqv = *reinterpret_cast<const float4*>(bq + cb + lgrp * 4);          \
        _Pragma("unroll")                                                           \
        for (int tt = 0; tt < 4; ++tt) {                                            \
            f32x4 d = {0.f, 0.f, 0.f, 0.f};                                         \
            _Pragma("unroll")                                                       \
            for (int kk = 0; kk < 4; ++kk)                                          \
                d = __builtin_amdgcn_mfma_f32_16x16x32_bf16(WF[kk], xb[tt][kk], d, 0, 0, 0); \
            int row = tt * 16 + lrow;                                               \
            if (cb < 128) {                                                         \
                int c = cb + lgrp * 4;                                              \
                short4v pk;                                                         \
                pk[0] = bfbits((d[0] + bqv.x) * SCALE_Q); pk[1] = bfbits((d[1] + bqv.y) * SCALE_Q); \
                pk[2] = bfbits((d[2] + bqv.z) * SCALE_Q); pk[3] = bfbits((d[3] + bqv.w) * SCALE_Q); \
                *reinterpret_cast<short4v*>(&bufA[row * 128 + (c ^ ((row & 7) << 3))]) = pk; \
            } else if (cb < 256) {                                                  \
                int c = cb - 128 + lgrp * 4;                                        \
                short4v pk;                                                         \
                pk[0] = bfbits(d[0] + bqv.x); pk[1] = bfbits(d[1] + bqv.y);         \
                pk[2] = bfbits(d[2] + bqv.z); pk[3] = bfbits(d[3] + bqv.w);         \
                *reinterpret_cast<short4v*>(&bufB[row * 128 + (c ^ ((row & 7) << 3))]) = pk; \
            } else {                                                                \
                int db = cb - 256 + lgrp * 4;                                       \
                bufC[tt * 2048 + (db + 0) * 16 + lrow] = __float2bfloat16(d[0] + bqv.x); \
                bufC[tt * 2048 + (db + 1) * 16 + lrow] = __float2bfloat16(d[1] + bqv.y); \
                bufC[tt * 2048 + (db + 2) * 16 + lrow] = __float2bfloat16(d[2] + bqv.z); \
                bufC[tt * 2048 + (db + 3) * 16 + lrow] = __float2bfloat16(d[3] + bqv.w); \
            }                                                                       \
        }                                                                           \
    }

#pragma unroll
    for (int j = 0; j < 2; ++j)
#pragma unroll
        for (int kk = 0; kk < 4; ++kk)
            wq1[j][kk] = gld8(wqt + (size_t)(qc + (j + 2) * 16 + lrow) * 128 + kk * 32 + lgrp * 8);
    QKV_TILE(wq0[0], 0) QKV_TILE(wq0[1], 1)
#pragma unroll
    for (int j = 0; j < 2; ++j)
#pragma unroll
        for (int kk = 0; kk < 4; ++kk)
            wq0[j][kk] = gld8(wqt + (size_t)(qc + (j + 4) * 16 + lrow) * 128 + kk * 32 + lgrp * 8);
    QKV_TILE(wq1[0], 2) QKV_TILE(wq1[1], 3)
    QKV_TILE(wq0[0], 4) QKV_TILE(wq0[1], 5)
    bar_lds();

    // ---- prefetch proj frags; scores + softmax + PV
    short8 wfp[2][4];
#pragma unroll
    for (int nt = 0; nt < 2; ++nt)
#pragma unroll
        for (int kk = 0; kk < 4; ++kk)
            wfp[nt][kk] = gld8(wpt + (size_t)(cb0 + nt * 16 + lrow) * 128 + kk * 32 + lgrp * 8);

    float p[4][4];
#pragma unroll
    for (int hh = 0; hh < 4; ++hh) {
        short8 aq = ldsA(bufA, wid * 16 + lrow, hh * 32 + lgrp * 8);
        short8 bk = ldsA(bufB, wid * 16 + lrow, hh * 32 + lgrp * 8);
        f32x4 z = {0.f, 0.f, 0.f, 0.f};
        f32x4 s = __builtin_amdgcn_mfma_f32_16x16x32_bf16(aq, bk, z, 0, 0, 0);
#pragma unroll
        for (int i = 0; i < 4; ++i) {
            float m_ = s[i];
            m_ = fmaxf(m_, __shfl_xor(m_, 1, 64));
            m_ = fmaxf(m_, __shfl_xor(m_, 2, 64));
            m_ = fmaxf(m_, __shfl_xor(m_, 4, 64));
            m_ = fmaxf(m_, __shfl_xor(m_, 8, 64));
            float e = __expf(s[i] - m_);
            float sum = e;
            sum += __shfl_xor(sum, 1, 64);
            sum += __shfl_xor(sum, 2, 64);
            sum += __shfl_xor(sum, 4, 64);
            sum += __shfl_xor(sum, 8, 64);
            p[hh][i] = e * __builtin_amdgcn_rcpf(sum);
        }
    }
    bf16* pl = bufB + wid * 2048;
#pragma unroll
    for (int hh = 0; hh < 4; ++hh)
#pragma unroll
        for (int i = 0; i < 4; ++i)
            pl[hh * 256 + (lgrp * 4 + i) * 16 + lrow] = __float2bfloat16(p[hh][i]);

    short8 z8 = {0, 0, 0, 0, 0, 0, 0, 0};
#pragma unroll
    for (int dt = 0; dt < 8; ++dt) {
        int hh = dt >> 1;
        short8 av = z8, bv = z8;
        if (lgrp < 2) {
            av = *reinterpret_cast<const short8*>(&bufC[wid * 2048 + (dt * 16 + lrow) * 16 + lgrp * 8]);
            bv = *reinterpret_cast<const short8*>(&pl[hh * 256 + lrow * 16 + lgrp * 8]);
        }
        f32x4 z = {0.f, 0.f, 0.f, 0.f};
        f32x4 o = __builtin_amdgcn_mfma_f32_16x16x32_bf16(av, bv, z, 0, 0, 0);
        int row = wid * 16 + lrow;
        int c = dt * 16 + lgrp * 4;
        short4v pk;
        pk[0] = bfbits(o[0]); pk[1] = bfbits(o[1]); pk[2] = bfbits(o[2]); pk[3] = bfbits(o[3]);
        *reinterpret_cast<short4v*>(&bufA[row * 128 + (c ^ ((row & 7) << 3))]) = pk;
    }
    bar_lds();   // attn-out done; vt/P reads done

    // ---- proj + residual (all in regs)
    short8 af[4][4];
#pragma unroll
    for (int tt = 0; tt < 4; ++tt)
#pragma unroll
        for (int kk = 0; kk < 4; ++kk)
            af[tt][kk] = ldsA(bufA, tt * 16 + lrow, kk * 32 + lgrp * 8);
    f32x4 hres[2][4];
#pragma unroll
    for (int nt = 0; nt < 2; ++nt) {
        float4 bpv = *reinterpret_cast<const float4*>(bp + cb0 + nt * 16 + lgrp * 4);
#pragma unroll
        for (int tt = 0; tt < 4; ++tt) {
            f32x4 d = {0.f, 0.f, 0.f, 0.f};
#pragma unroll
            for (int kk = 0; kk < 4; ++kk)
                d = __builtin_amdgcn_mfma_f32_16x16x32_bf16(wfp[nt][kk], af[tt][kk], d, 0, 0, 0);
            f32x4 r = hraw[nt][tt];
            r[0] += bpv.x + d[0]; r[1] += bpv.y + d[1];
            r[2] += bpv.z + d[2]; r[3] += bpv.w + d[3];
            hres[nt][tt] = r;
        }
    }

    // ---- LN2 -> xn2 in bufB
#pragma unroll
    for (int tt = 0; tt < 4; ++tt) {
        float s = 0.f, q = 0.f;
#pragma unroll
        for (int nt = 0; nt < 2; ++nt)
#pragma unroll
            for (int i = 0; i < 4; ++i) { float v = hres[nt][tt][i]; s += v; q += v * v; }
        s += __shfl_xor(s, 16, 64); s += __shfl_xor(s, 32, 64);
        q += __shfl_xor(q, 16, 64); q += __shfl_xor(q, 32, 64);
        if (lgrp == 0) { float2 t2; t2.x = s; t2.y = q; ws[wid * 64 + tt * 16 + lrow] = t2; }
    }
    bar_lds();
    short8 w1f[2][2][4];
    {
        float mu[4], rstd[4];
#pragma unroll
        for (int tt = 0; tt < 4; ++tt) {
            float s = 0.f, q = 0.f;
#pragma unroll
            for (int w = 0; w < 4; ++w) {
                float2 t2 = ws[w * 64 + tt * 16 + lrow];
                s += t2.x; q += t2.y;
            }
            float m = s * (1.f / 128.f);
            mu[tt] = m;
            rstd[tt] = rsqrtf(q * (1.f / 128.f) - m * m + 1e-5f);
        }
        float4 gv[2], bev[2];
#pragma unroll
        for (int nt = 0; nt < 2; ++nt) {
            gv[nt]  = *reinterpret_cast<const float4*>(g2 + cb0 + nt * 16 + lgrp * 4);
            bev[nt] = *reinterpret_cast<const float4*>(be2 + cb0 + nt * 16 + lgrp * 4);
        }
#pragma unroll
        for (int nt = 0; nt < 2; ++nt)
#pragma unroll
            for (int tt = 0; tt < 4; ++tt) {
                short4v pk;
                pk[0] = bfbits((hres[nt][tt][0] - mu[tt]) * rstd[tt] * gv[nt].x + bev[nt].x);
                pk[1] = bfbits((hres[nt][tt][1] - mu[tt]) * rstd[tt] * gv[nt].y + bev[nt].y);
                pk[2] = bfbits((hres[nt][tt][2] - mu[tt]) * rstd[tt] * gv[nt].z + bev[nt].z);
                pk[3] = bfbits((hres[nt][tt][3] - mu[tt]) * rstd[tt] * gv[nt].w + bev[nt].w);
                int row = tt * 16 + lrow;
                int c = cb0 + nt * 16 + lgrp * 4;
                *reinterpret_cast<short4v*>(&bufB[row * 128 + (c ^ ((row & 7) << 3))]) = pk;
            }
    }
    // prefetch mlp1 chunk-0 frags (in flight across next barrier)
#pragma unroll
    for (int nt = 0; nt < 2; ++nt)
#pragma unroll
        for (int kk = 0; kk < 4; ++kk)
            w1f[0][nt][kk] = gld8(w1t + (size_t)(cb0 + nt * 16 + lrow) * 128 + kk * 32 + lgrp * 8);
    bar_lds();

    // ---- MLP: 4 chunks of 128; u ping-pongs bufA/bufC; 1 barrier per chunk
    f32x4 acc2[2][4];
#pragma unroll
    for (int nt = 0; nt < 2; ++nt)
#pragma unroll
        for (int tt = 0; tt < 4; ++tt) acc2[nt][tt] = (f32x4){0.f, 0.f, 0.f, 0.f};

#pragma unroll
    for (int ch = 0; ch < 4; ++ch) {
        bf16* UB = (ch & 1) ? bufC : bufA;
        short8 w2f[2][4];
#pragma unroll
        for (int nt = 0; nt < 2; ++nt)
#pragma unroll
            for (int kk = 0; kk < 4; ++kk)
                w2f[nt][kk] = gld8(w2t + (size_t)(cb0 + nt * 16 + lrow) * 512 + ch * 128 + kk * 32 + lgrp * 8);
        // mlp1: u = gelu(xn2 @ w1 + b1) -> UB
        float4 b1v[2];
#pragma unroll
        for (int nt = 0; nt < 2; ++nt)
            b1v[nt] = *reinterpret_cast<const float4*>(b1 + ch * 128 + cb0 + nt * 16 + lgrp * 4);
#pragma unroll
        for (int tt = 0; tt < 4; ++tt) {
            short8 xf[4];
#pragma unroll
            for (int kk = 0; kk < 4; ++kk)
                xf[kk] = ldsA(bufB, tt * 16 + lrow, kk * 32 + lgrp * 8);
#pragma unroll
            for (int nt = 0; nt < 2; ++nt) {
                f32x4 d = {0.f, 0.f, 0.f, 0.f};
#pragma unroll
                for (int kk = 0; kk < 4; ++kk)
                    d = __builtin_amdgcn_mfma_f32_16x16x32_bf16(w1f[ch & 1][nt][kk], xf[kk], d, 0, 0, 0);
                short4v pk;
                pk[0] = bfbits(gelu_f(d[0] + b1v[nt].x)); pk[1] = bfbits(gelu_f(d[1] + b1v[nt].y));
                pk[2] = bfbits(gelu_f(d[2] + b1v[nt].z)); pk[3] = bfbits(gelu_f(d[3] + b1v[nt].w));
                int row = tt * 16 + lrow;
                int c = cb0 + nt * 16 + lgrp * 4;
                *reinterpret_cast<short4v*>(&UB[row * 128 + (c ^ ((row & 7) << 3))]) = pk;
            }
        }
        if (ch < 3) {
#pragma unroll
            for (int nt = 0; nt < 2; ++nt)
#pragma unroll
                for (int kk = 0; kk < 4; ++kk)
                    w1f[(ch + 1) & 1][nt][kk] =
                        gld8(w1t + (size_t)((ch + 1) * 128 + cb0 + nt * 16 + lrow) * 128 + kk * 32 + lgrp * 8);
        }
        bar_lds();                 // u(ch) visible; u(ch-2) reads (pre-prev bar) safe
        // mlp2: acc2 += u @ w2
#pragma unroll
        for (int tt = 0; tt < 4; ++tt) {
            short8 uf[4];
#pragma unroll
            for (int kk = 0; kk < 4; ++kk)
                uf[kk] = ldsA(UB, tt * 16 + lrow, kk * 32 + lgrp * 8);
#pragma unroll
            for (int nt = 0; nt < 2; ++nt)
#pragma unroll
                for (int kk = 0; kk < 4; ++kk)
                    acc2[nt][tt] = __builtin_amdgcn_mfma_f32_16x16x32_bf16(
                        w2f[nt][kk], uf[kk], acc2[nt][tt], 0, 0, 0);
        }
    }

    if (MODE == 0) {
        // ---- epilogue: h = hres + b2 + acc2
#pragma unroll
        for (int nt = 0; nt < 2; ++nt) {
            const int n0 = cb0 + nt * 16 + lgrp * 4;
            float4 b2v = *reinterpret_cast<const float4*>(b2 + n0);
#pragma unroll
            for (int tt = 0; tt < 4; ++tt) {
                int tok = base + OFFSET + tt * 16 + lrow; if (tok >= NPIX) tok -= NPIX;
                float4 ov;
                ov.x = hres[nt][tt][0] + b2v.x + acc2[nt][tt][0];
                ov.y = hres[nt][tt][1] + b2v.y + acc2[nt][tt][1];
                ov.z = hres[nt][tt][2] + b2v.z + acc2[nt][tt][2];
                ov.w = hres[nt][tt][3] + b2v.w + acc2[nt][tt][3];
                *reinterpret_cast<float4*>(h + (size_t)tok * 128 + n0) = ov;
            }
        }
    } else {
        // ---- epilogue: out = x + (hfinal) @ wff2 + bff2 (ff2 fused)
        short8 wff[4];
#pragma unroll
        for (int kk = 0; kk < 4; ++kk)
            wff[kk] = gld8(wf2t + (size_t)(wid * 16 + lrow) * 128 + kk * 32 + lgrp * 8);
        float4 xv[4];
#pragma unroll
        for (int tt = 0; tt < 4; ++tt) {
            int tok = base + OFFSET + tt * 16 + lrow; if (tok >= NPIX) tok -= NPIX;
            xv[tt] = *reinterpret_cast<const float4*>(x + (size_t)tok * 64 + wid * 16 + lgrp * 4);
        }
        bar_lds();   // ensure all mlp2 u-reads done before bufB overwrite
#pragma unroll
        for (int nt = 0; nt < 2; ++nt) {
            const int n0 = cb0 + nt * 16 + lgrp * 4;
            float4 b2v = *reinterpret_cast<const float4*>(b2 + n0);
#pragma unroll
            for (int tt = 0; tt < 4; ++tt) {
                short4v pk;
                pk[0] = bfbits(hres[nt][tt][0] + b2v.x + acc2[nt][tt][0]);
                pk[1] = bfbits(hres[nt][tt][1] + b2v.y + acc2[nt][tt][1]);
                pk[2] = bfbits(hres[nt][tt][2] + b2v.z + acc2[nt][tt][2]);
                pk[3] = bfbits(hres[nt][tt][3] + b2v.w + acc2[nt][tt][3]);
                int row = tt * 16 + lrow;
                int c = cb0 + nt * 16 + lgrp * 4;
                *reinterpret_cast<short4v*>(&bufB[row * 128 + (c ^ ((row & 7) << 3))]) = pk;
            }
        }
        bar_lds();
        float4 bfv = *reinterpret_cast<const float4*>(bf2 + wid * 16 + lgrp * 4);
#pragma unroll
        for (int tt = 0; tt < 4; ++tt) {
            short8 bfr[4];
#pragma unroll
            for (int kk = 0; kk < 4; ++kk)
                bfr[kk] = ldsA(bufB, tt * 16 + lrow, kk * 32 + lgrp * 8);
            f32x4 d = {0.f, 0.f, 0.f, 0.f};
#pragma unroll
            for (int kk = 0; kk < 4; ++kk)
                d = __builtin_amdgcn_mfma_f32_16x16x32_bf16(wff[kk], bfr[kk], d, 0, 0, 0);
            int tok = base + OFFSET + tt * 16 + lrow; if (tok >= NPIX) tok -= NPIX;
            float4 ov;
            ov.x = xv[tt].x + bfv.x + d[0]; ov.y = xv[tt].y + bfv.y + d[1];
            ov.z = xv[tt].z + bfv.z + d[2]; ov.w = xv[tt].w + bfv.w + d[3];
            *reinterpret_cast<float4*>(out + (size_t)tok * 64 + wid * 16 + lgrp * 4) = ov;
        }
    }
#undef QKV_TILE
}

extern "C" void kernel_launch(void* const* d_in, const int* in_sizes, int n_in,
                              void* d_out, int out_size, void* d_ws, size_t ws_size,
                              hipStream_t stream) {
    (void)in_sizes; (void)n_in; (void)out_size; (void)ws_size;
    const float* x      = (const float*)d_in[0];
    const float* w_ff1  = (const float*)d_in[1];
    const float* b_ff1  = (const float*)d_in[2];
    const float* ln1_g  = (const float*)d_in[3];
    const float* ln1_b  = (const float*)d_in[4];
    const float* w_qkv  = (const float*)d_in[5];
    const float* b_qkv  = (const float*)d_in[6];
    const float* w_proj = (const float*)d_in[7];
    const float* b_proj = (const float*)d_in[8];
    const float* ln2_g  = (const float*)d_in[9];
    const float* ln2_b  = (const float*)d_in[10];
    const float* w_mlp1 = (const float*)d_in[11];
    const float* b_mlp1 = (const float*)d_in[12];
    const float* w_mlp2 = (const float*)d_in[13];
    const float* b_mlp2 = (const float*)d_in[14];
    const float* w_ff2  = (const float*)d_in[15];
    const float* b_ff2  = (const float*)d_in[16];
    float* out = (float*)d_out;

    float* h = (float*)d_ws;                                   // [NPIX,128] fp32
    bf16* wbf = (bf16*)((char*)d_ws + (size_t)NPIX * 128 * 4);
    bf16* ff1t  = wbf;            // [128][64]
    bf16* qkvt  = wbf + 8192;     // 2x[384][128]
    bf16* projt = wbf + 106496;   // 2x[128][128]
    bf16* mlp1t = wbf + 139264;   // 2x[512][128]
    bf16* mlp2t = wbf + 270336;   // 2x[128][512]
    bf16* ff2t  = wbf + 401408;   // [64][128]

    k_convert<<<1600, dim3(256), 0, stream>>>(w_ff1, w_qkv, w_proj, w_mlp1, w_mlp2, w_ff2, wbf);

    const int NB = NPIX / 64;  // 3072
    k_block<0, 0><<<NB, dim3(256), 0, stream>>>(x, h,
        ff1t, b_ff1,
        ln1_g, ln1_b, qkvt, b_qkv, projt, b_proj,
        ln2_g, ln2_b, mlp1t, b_mlp1, mlp2t, b_mlp2,
        ff2t, b_ff2, out);

    k_block<8, 1><<<NB, dim3(256), 0, stream>>>(x, h,
        ff1t, b_ff1,
        ln1_g + 128, ln1_b + 128, qkvt + 49152, b_qkv + 384, projt + 16384, b_proj + 128,
        ln2_g + 128, ln2_b + 128, mlp1t + 65536, b_mlp1 + 512, mlp2t + 65536, b_mlp2 + 128,
        ff2t, b_ff2, out);
}

// Round 9
// 407.695 us; speedup vs baseline: 2.8175x; 1.3303x over previous
//
#include <hip/hip_runtime.h>
#include <hip/hip_bf16.h>
#include <math.h>

#define NPIX 196608
#define SCALE_Q 0.17677669529663687f

typedef __attribute__((ext_vector_type(4))) float f32x4;
typedef __attribute__((ext_vector_type(8))) short short8;
typedef __attribute__((ext_vector_type(4))) short short4v;
typedef __hip_bfloat16 bf16;

__device__ __forceinline__ float gelu_f(float x) {          // accurate (ff1)
    float yy = 1.5957691216057308f * (x + 0.044715f * x * x * x);
    float e = __expf(yy);
    return x - x * __builtin_amdgcn_rcpf(e + 1.0f);
}
__device__ __forceinline__ float gelu_fast(float x) {       // sigmoid form (mlp1)
    float e = __expf(-1.702f * x);
    return x * __builtin_amdgcn_rcpf(1.0f + e);
}

__device__ __forceinline__ short bfbits(float f) {
    bf16 h = __float2bfloat16(f);
    return *reinterpret_cast<short*>(&h);
}

__device__ __forceinline__ short8 ldsA(const bf16* buf, int row, int el) {
    return *reinterpret_cast<const short8*>(buf + row * 128 + (el ^ ((row & 7) << 3)));
}
__device__ __forceinline__ short8 ldsA64(const bf16* buf, int row, int el) {
    return *reinterpret_cast<const short8*>(buf + row * 64 + (el ^ ((row & 7) << 3)));
}
__device__ __forceinline__ short8 gld8(const bf16* p) {
    return *reinterpret_cast<const short8*>(p);
}

// LDS-only barrier (no vmcnt drain, no sched pinning — m141 lesson)
__device__ __forceinline__ void bar_lds() {
    asm volatile("s_waitcnt lgkmcnt(0)" ::: "memory");
    __builtin_amdgcn_s_barrier();
}

// ---------------- weight convert to bf16 transposed images (all linear) ---
__global__ __launch_bounds__(256) void k_convert(
    const float* __restrict__ wff1, const float* __restrict__ wqkv,
    const float* __restrict__ wproj, const float* __restrict__ wmlp1,
    const float* __restrict__ wmlp2, const float* __restrict__ wff2,
    bf16* __restrict__ dst)
{
    int gid = blockIdx.x * 256 + threadIdx.x;
    if (gid < 8192) {                       // ff1t [128 n][64 k]
        int n = gid >> 6, k = gid & 63;
        dst[gid] = __float2bfloat16(wff1[k * 128 + n]);
    } else if (gid < 106496) {              // qkvt [l][384 n][128 k]
        int r = gid - 8192; int l = r / 49152; r -= l * 49152;
        int n = r >> 7, k = r & 127;
        dst[gid] = __float2bfloat16(wqkv[l * 49152 + k * 384 + n]);
    } else if (gid < 139264) {              // projt [l][128 n][128 k]
        int r = gid - 106496; int l = r / 16384; r -= l * 16384;
        int n = r >> 7, k = r & 127;
        dst[gid] = __float2bfloat16(wproj[l * 16384 + k * 128 + n]);
    } else if (gid < 270336) {              // mlp1t [l][512 n][128 k]
        int r = gid - 139264; int l = r >> 16; r &= 65535;
        int n = r >> 7, k = r & 127;
        dst[gid] = __float2bfloat16(wmlp1[l * 65536 + k * 512 + n]);
    } else if (gid < 401408) {              // mlp2t [l][128 n][512 k]
        int r = gid - 270336; int l = r >> 16; r &= 65535;
        int n = r >> 9, k = r & 511;
        dst[gid] = __float2bfloat16(wmlp2[l * 65536 + k * 128 + n]);
    } else if (gid < 409600) {              // ff2t [64 n][128 k]
        int r = gid - 401408;
        int n = r >> 7, k = r & 127;
        dst[gid] = __float2bfloat16(wff2[k * 64 + n]);
    }
}

// ---------------- fused block kernel ------------------------------------
// MODE 0: ff1 fused at head (reads x), writes h at tail.
// MODE 1: reads h at head, ff2 fused at tail (writes out).
template <int OFFSET, int MODE>
__global__ __launch_bounds__(256, 3) void k_block(
    const float* __restrict__ x, float* __restrict__ h,
    const bf16* __restrict__ wf1t, const float* __restrict__ bf1,
    const float* __restrict__ g1, const float* __restrict__ be1,
    const bf16* __restrict__ wqt, const float* __restrict__ bq,
    const bf16* __restrict__ wpt, const float* __restrict__ bp,
    const float* __restrict__ g2, const float* __restrict__ be2,
    const bf16* __restrict__ w1t, const float* __restrict__ b1,
    const bf16* __restrict__ w2t, const float* __restrict__ b2,
    const bf16* __restrict__ wf2t, const float* __restrict__ bf2,
    float* __restrict__ out)
{
    __shared__ __align__(16) bf16 bufA[8192];  // xn1 -> q/P/attn-out -> u(even)
    __shared__ __align__(16) bf16 bufB[8192];  // k -> xn2 -> hfinal(M1)
    __shared__ __align__(16) bf16 bufC[8192];  // xs(M0)/LN partials -> vt -> u(odd)
    const int tid = threadIdx.x, base = blockIdx.x * 64;
    const int wid = tid >> 6, lrow = tid & 15, lgrp = (tid >> 4) & 3;
    const int cb0 = wid * 32;                  // wave's n-slice (proj/mlp split)
    const int hc  = wid * 32;                  // wave's head col base (attention)

    f32x4 hraw[2][4];   // [nt][tt]: n = cb0+nt*16+lgrp*4+i, token tt*16+lrow

    if (MODE == 0) {
        short8 wf1[2][2];
#pragma unroll
        for (int nt = 0; nt < 2; ++nt)
#pragma unroll
            for (int kk = 0; kk < 2; ++kk)
                wf1[nt][kk] = gld8(wf1t + (size_t)(cb0 + nt * 16 + lrow) * 64 + kk * 32 + lgrp * 8);
        {
            int row = tid >> 2, q = tid & 3;
#pragma unroll
            for (int s = 0; s < 2; ++s) {
                int gg = q + s * 4;
                const float4* src = reinterpret_cast<const float4*>(x + (size_t)(base + row) * 64 + gg * 8);
                float4 v0 = src[0], v1 = src[1];
                short8 w;
                w[0] = bfbits(v0.x); w[1] = bfbits(v0.y); w[2] = bfbits(v0.z); w[3] = bfbits(v0.w);
                w[4] = bfbits(v1.x); w[5] = bfbits(v1.y); w[6] = bfbits(v1.z); w[7] = bfbits(v1.w);
                *reinterpret_cast<short8*>(&bufC[row * 64 + ((gg * 8) ^ ((row & 7) << 3))]) = w;
            }
        }
        bar_lds();
        short8 xb1[4][2];
#pragma unroll
        for (int tt = 0; tt < 4; ++tt)
#pragma unroll
            for (int kk = 0; kk < 2; ++kk)
                xb1[tt][kk] = ldsA64(bufC, tt * 16 + lrow, kk * 32 + lgrp * 8);
        bar_lds();   // xs reads done; bufC reusable
#pragma unroll
        for (int nt = 0; nt < 2; ++nt) {
            float4 bv = *reinterpret_cast<const float4*>(bf1 + cb0 + nt * 16 + lgrp * 4);
#pragma unroll
            for (int tt = 0; tt < 4; ++tt) {
                f32x4 d = {0.f, 0.f, 0.f, 0.f};
#pragma unroll
                for (int kk = 0; kk < 2; ++kk)
                    d = __builtin_amdgcn_mfma_f32_16x16x32_bf16(wf1[nt][kk], xb1[tt][kk], d, 0, 0, 0);
                f32x4 r;
                r[0] = gelu_f(d[0] + bv.x); r[1] = gelu_f(d[1] + bv.y);
                r[2] = gelu_f(d[2] + bv.z); r[3] = gelu_f(d[3] + bv.w);
                hraw[nt][tt] = r;
            }
        }
    } else {
#pragma unroll
        for (int nt = 0; nt < 2; ++nt)
#pragma unroll
            for (int tt = 0; tt < 4; ++tt) {
                int tok = base + OFFSET + tt * 16 + lrow; if (tok >= NPIX) tok -= NPIX;
                float4 hv = *reinterpret_cast<const float4*>(h + (size_t)tok * 128 + cb0 + nt * 16 + lgrp * 4);
                f32x4 r; r[0] = hv.x; r[1] = hv.y; r[2] = hv.z; r[3] = hv.w;
                hraw[nt][tt] = r;
            }
    }

    // ---- LN1 (cross-wave over n) -> xn1 in bufA
    float2* ws = reinterpret_cast<float2*>(bufC);
#pragma unroll
    for (int tt = 0; tt < 4; ++tt) {
        float s = 0.f, q = 0.f;
#pragma unroll
        for (int nt = 0; nt < 2; ++nt)
#pragma unroll
            for (int i = 0; i < 4; ++i) { float v = hraw[nt][tt][i]; s += v; q += v * v; }
        s += __shfl_xor(s, 16, 64); s += __shfl_xor(s, 32, 64);
        q += __shfl_xor(q, 16, 64); q += __shfl_xor(q, 32, 64);
        if (lgrp == 0) { float2 t2; t2.x = s; t2.y = q; ws[wid * 64 + tt * 16 + lrow] = t2; }
    }
    bar_lds();
    {
        float mu[4], rstd[4];
#pragma unroll
        for (int tt = 0; tt < 4; ++tt) {
            float s = 0.f, q = 0.f;
#pragma unroll
            for (int w = 0; w < 4; ++w) {
                float2 t2 = ws[w * 64 + tt * 16 + lrow];
                s += t2.x; q += t2.y;
            }
            float m = s * (1.f / 128.f);
            mu[tt] = m;
            rstd[tt] = rsqrtf(q * (1.f / 128.f) - m * m + 1e-5f);
        }
        float4 gv[2], bev[2];
#pragma unroll
        for (int nt = 0; nt < 2; ++nt) {
            gv[nt]  = *reinterpret_cast<const float4*>(g1 + cb0 + nt * 16 + lgrp * 4);
            bev[nt] = *reinterpret_cast<const float4*>(be1 + cb0 + nt * 16 + lgrp * 4);
        }
#pragma unroll
        for (int nt = 0; nt < 2; ++nt)
#pragma unroll
            for (int tt = 0; tt < 4; ++tt) {
                short4v pk;
                pk[0] = bfbits((hraw[nt][tt][0] - mu[tt]) * rstd[tt] * gv[nt].x + bev[nt].x);
                pk[1] = bfbits((hraw[nt][tt][1] - mu[tt]) * rstd[tt] * gv[nt].y + bev[nt].y);
                pk[2] = bfbits((hraw[nt][tt][2] - mu[tt]) * rstd[tt] * gv[nt].z + bev[nt].z);
                pk[3] = bfbits((hraw[nt][tt][3] - mu[tt]) * rstd[tt] * gv[nt].w + bev[nt].w);
                int row = tt * 16 + lrow;
                int c = cb0 + nt * 16 + lgrp * 4;
                *reinterpret_cast<short4v*>(&bufA[row * 128 + (c ^ ((row & 7) << 3))]) = pk;
            }
    }
    // long-distance prefetch: proj frags (consumed after attention)
    short8 wfp[2][4];
#pragma unroll
    for (int nt = 0; nt < 2; ++nt)
#pragma unroll
        for (int kk = 0; kk < 4; ++kk)
            wfp[nt][kk] = gld8(wpt + (size_t)(cb0 + nt * 16 + lrow) * 128 + kk * 32 + lgrp * 8);
    bar_lds();

    short8 xb[4][4];
#pragma unroll
    for (int tt = 0; tt < 4; ++tt)
#pragma unroll
        for (int kk = 0; kk < 4; ++kk)
            xb[tt][kk] = ldsA(bufA, tt * 16 + lrow, kk * 32 + lgrp * 8);
    bar_lds();   // xn1 reads done before q overwrites bufA

    // ======== per-head attention: wave w = head w, NO cross-wave barriers =====
    // q tiles (head slice [hc, hc+32)) -> bufA (swizzled)
#pragma unroll
    for (int qt = 0; qt < 2; ++qt) {
        const int cb = hc + qt * 16;
        float4 bqv = *reinterpret_cast<const float4*>(bq + cb + lgrp * 4);
        short8 wf[4];
#pragma unroll
        for (int kk = 0; kk < 4; ++kk)
            wf[kk] = gld8(wqt + (size_t)(cb + lrow) * 128 + kk * 32 + lgrp * 8);
#pragma unroll
        for (int tt = 0; tt < 4; ++tt) {
            f32x4 d = {0.f, 0.f, 0.f, 0.f};
#pragma unroll
            for (int kk = 0; kk < 4; ++kk)
                d = __builtin_amdgcn_mfma_f32_16x16x32_bf16(wf[kk], xb[tt][kk], d, 0, 0, 0);
            int row = tt * 16 + lrow;
            int c = cb + lgrp * 4;
            short4v pk;
            pk[0] = bfbits((d[0] + bqv.x) * SCALE_Q); pk[1] = bfbits((d[1] + bqv.y) * SCALE_Q);
            pk[2] = bfbits((d[2] + bqv.z) * SCALE_Q); pk[3] = bfbits((d[3] + bqv.w) * SCALE_Q);
            *reinterpret_cast<short4v*>(&bufA[row * 128 + (c ^ ((row & 7) << 3))]) = pk;
        }
    }
    // k tiles -> bufB (swizzled)
#pragma unroll
    for (int kt = 0; kt < 2; ++kt) {
        const int cb = hc + kt * 16;
        float4 bqv = *reinterpret_cast<const float4*>(bq + 128 + cb + lgrp * 4);
        short8 wf[4];
#pragma unroll
        for (int kk = 0; kk < 4; ++kk)
            wf[kk] = gld8(wqt + (size_t)(128 + cb + lrow) * 128 + kk * 32 + lgrp * 8);
#pragma unroll
        for (int tt = 0; tt < 4; ++tt) {
            f32x4 d = {0.f, 0.f, 0.f, 0.f};
#pragma unroll
            for (int kk = 0; kk < 4; ++kk)
                d = __builtin_amdgcn_mfma_f32_16x16x32_bf16(wf[kk], xb[tt][kk], d, 0, 0, 0);
            int row = tt * 16 + lrow;
            int c = cb + lgrp * 4;
            short4v pk;
            pk[0] = bfbits(d[0] + bqv.x); pk[1] = bfbits(d[1] + bqv.y);
            pk[2] = bfbits(d[2] + bqv.z); pk[3] = bfbits(d[3] + bqv.w);
            *reinterpret_cast<short4v*>(&bufB[row * 128 + (c ^ ((row & 7) << 3))]) = pk;
        }
    }
    // v tiles -> wave-private vt slice in bufC: vt[d 32][tok 64]
    bf16* vt = bufC + wid * 2048;
#pragma unroll
    for (int vt_ = 0; vt_ < 2; ++vt_) {
        const int cb = hc + vt_ * 16;
        float4 bqv = *reinterpret_cast<const float4*>(bq + 256 + cb + lgrp * 4);
        short8 wf[4];
#pragma unroll
        for (int kk = 0; kk < 4; ++kk)
            wf[kk] = gld8(wqt + (size_t)(256 + cb + lrow) * 128 + kk * 32 + lgrp * 8);
#pragma unroll
        for (int tt = 0; tt < 4; ++tt) {
            f32x4 d = {0.f, 0.f, 0.f, 0.f};
#pragma unroll
            for (int kk = 0; kk < 4; ++kk)
                d = __builtin_amdgcn_mfma_f32_16x16x32_bf16(wf[kk], xb[tt][kk], d, 0, 0, 0);
#pragma unroll
            for (int i = 0; i < 4; ++i)
                vt[(vt_ * 16 + lgrp * 4 + i) * 64 + tt * 16 + lrow] =
                    __float2bfloat16(d[i] + ((const float*)&bqv)[i]);
        }
    }

    // per-window: scores (swapped operands) -> softmax -> P -> PV (all wave-local)
#pragma unroll
    for (int tt = 0; tt < 4; ++tt) {
        const int row = tt * 16 + lrow;
        const int swr = (lrow & 7) << 3;
        short8 aq = *reinterpret_cast<const short8*>(&bufA[row * 128 + ((hc + lgrp * 8) ^ swr)]);
        short8 bk = *reinterpret_cast<const short8*>(&bufB[row * 128 + ((hc + lgrp * 8) ^ swr)]);
        f32x4 z = {0.f, 0.f, 0.f, 0.f};
        // D[tok_k][tok_q]: lane col = tok_q = lrow, rows tok_k = lgrp*4+i
        f32x4 s = __builtin_amdgcn_mfma_f32_16x16x32_bf16(bk, aq, z, 0, 0, 0);
        float m_ = fmaxf(fmaxf(s[0], s[1]), fmaxf(s[2], s[3]));
        m_ = fmaxf(m_, __shfl_xor(m_, 16, 64));
        m_ = fmaxf(m_, __shfl_xor(m_, 32, 64));
        float e0 = __expf(s[0] - m_), e1 = __expf(s[1] - m_);
        float e2 = __expf(s[2] - m_), e3 = __expf(s[3] - m_);
        float sum = e0 + e1 + e2 + e3;
        sum += __shfl_xor(sum, 16, 64);
        sum += __shfl_xor(sum, 32, 64);
        float r = __builtin_amdgcn_rcpf(sum);
        // P[q=lrow][k=lgrp*4+i] -> swizzled store into dead q slice of bufA
        short4v pp;
        pp[0] = bfbits(e0 * r); pp[1] = bfbits(e1 * r);
        pp[2] = bfbits(e2 * r); pp[3] = bfbits(e3 * r);
        *reinterpret_cast<short4v*>(&bufA[row * 128 + ((hc + lgrp * 4) ^ swr)]) = pp;

        // PV: A = vt[d][key], B = P[key][q]; keys 16..31 zero (lgrp>=2)
        short8 z8 = {0, 0, 0, 0, 0, 0, 0, 0};
        short8 bp_ = z8;
        if (lgrp < 2)
            bp_ = *reinterpret_cast<const short8*>(&bufA[row * 128 + ((hc + lgrp * 8) ^ swr)]);
#pragma unroll
        for (int dt = 0; dt < 2; ++dt) {
            short8 av = z8;
            if (lgrp < 2)
                av = *reinterpret_cast<const short8*>(&vt[(dt * 16 + lrow) * 64 + tt * 16 + lgrp * 8]);
            f32x4 o = __builtin_amdgcn_mfma_f32_16x16x32_bf16(av, bp_, z, 0, 0, 0);
            // attn-out [tok][hc + dt*16 + lgrp*4 + i] swizzled (overwrites P/q)
            short4v pk;
            pk[0] = bfbits(o[0]); pk[1] = bfbits(o[1]); pk[2] = bfbits(o[2]); pk[3] = bfbits(o[3]);
            *reinterpret_cast<short4v*>(&bufA[row * 128 + ((hc + dt * 16 + lgrp * 4) ^ swr)]) = pk;
        }
    }
    bar_lds();   // attn-out complete across waves

    // ---- proj + residual (n-split; wfp prefetched far above)
    short8 af[4][4];
#pragma unroll
    for (int tt = 0; tt < 4; ++tt)
#pragma unroll
        for (int kk = 0; kk < 4; ++kk)
            af[tt][kk] = ldsA(bufA, tt * 16 + lrow, kk * 32 + lgrp * 8);
    f32x4 hres[2][4];
#pragma unroll
    for (int nt = 0; nt < 2; ++nt) {
        float4 bpv = *reinterpret_cast<const float4*>(bp + cb0 + nt * 16 + lgrp * 4);
#pragma unroll
        for (int tt = 0; tt < 4; ++tt) {
            f32x4 d = {0.f, 0.f, 0.f, 0.f};
#pragma unroll
            for (int kk = 0; kk < 4; ++kk)
                d = __builtin_amdgcn_mfma_f32_16x16x32_bf16(wfp[nt][kk], af[tt][kk], d, 0, 0, 0);
            f32x4 r = hraw[nt][tt];
            r[0] += bpv.x + d[0]; r[1] += bpv.y + d[1];
            r[2] += bpv.z + d[2]; r[3] += bpv.w + d[3];
            hres[nt][tt] = r;
        }
    }

    // ---- LN2 -> xn2 in bufB
#pragma unroll
    for (int tt = 0; tt < 4; ++tt) {
        float s = 0.f, q = 0.f;
#pragma unroll
        for (int nt = 0; nt < 2; ++nt)
#pragma unroll
            for (int i = 0; i < 4; ++i) { float v = hres[nt][tt][i]; s += v; q += v * v; }
        s += __shfl_xor(s, 16, 64); s += __shfl_xor(s, 32, 64);
        q += __shfl_xor(q, 16, 64); q += __shfl_xor(q, 32, 64);
        if (lgrp == 0) { float2 t2; t2.x = s; t2.y = q; ws[wid * 64 + tt * 16 + lrow] = t2; }
    }
    bar_lds();
    short8 w1f[2][2][4];
    {
        float mu[4], rstd[4];
#pragma unroll
        for (int tt = 0; tt < 4; ++tt) {
            float s = 0.f, q = 0.f;
#pragma unroll
            for (int w = 0; w < 4; ++w) {
                float2 t2 = ws[w * 64 + tt * 16 + lrow];
                s += t2.x; q += t2.y;
            }
            float m = s * (1.f / 128.f);
            mu[tt] = m;
            rstd[tt] = rsqrtf(q * (1.f / 128.f) - m * m + 1e-5f);
        }
        float4 gv[2], bev[2];
#pragma unroll
        for (int nt = 0; nt < 2; ++nt) {
            gv[nt]  = *reinterpret_cast<const float4*>(g2 + cb0 + nt * 16 + lgrp * 4);
            bev[nt] = *reinterpret_cast<const float4*>(be2 + cb0 + nt * 16 + lgrp * 4);
        }
#pragma unroll
        for (int nt = 0; nt < 2; ++nt)
#pragma unroll
            for (int tt = 0; tt < 4; ++tt) {
                short4v pk;
                pk[0] = bfbits((hres[nt][tt][0] - mu[tt]) * rstd[tt] * gv[nt].x + bev[nt].x);
                pk[1] = bfbits((hres[nt][tt][1] - mu[tt]) * rstd[tt] * gv[nt].y + bev[nt].y);
                pk[2] = bfbits((hres[nt][tt][2] - mu[tt]) * rstd[tt] * gv[nt].z + bev[nt].z);
                pk[3] = bfbits((hres[nt][tt][3] - mu[tt]) * rstd[tt] * gv[nt].w + bev[nt].w);
                int row = tt * 16 + lrow;
                int c = cb0 + nt * 16 + lgrp * 4;
                *reinterpret_cast<short4v*>(&bufB[row * 128 + (c ^ ((row & 7) << 3))]) = pk;
            }
    }
#pragma unroll
    for (int nt = 0; nt < 2; ++nt)
#pragma unroll
        for (int kk = 0; kk < 4; ++kk)
            w1f[0][nt][kk] = gld8(w1t + (size_t)(cb0 + nt * 16 + lrow) * 128 + kk * 32 + lgrp * 8);
    bar_lds();

    // ---- MLP: 4 chunks of 128; u ping-pongs bufA/bufC; 1 barrier per chunk
    f32x4 acc2[2][4];
#pragma unroll
    for (int nt = 0; nt < 2; ++nt)
#pragma unroll
        for (int tt = 0; tt < 4; ++tt) acc2[nt][tt] = (f32x4){0.f, 0.f, 0.f, 0.f};

#pragma unroll
    for (int ch = 0; ch < 4; ++ch) {
        bf16* UB = (ch & 1) ? bufC : bufA;
        short8 w2f[2][4];
#pragma unroll
        for (int nt = 0; nt < 2; ++nt)
#pragma unroll
            for (int kk = 0; kk < 4; ++kk)
                w2f[nt][kk] = gld8(w2t + (size_t)(cb0 + nt * 16 + lrow) * 512 + ch * 128 + kk * 32 + lgrp * 8);
        float4 b1v[2];
#pragma unroll
        for (int nt = 0; nt < 2; ++nt)
            b1v[nt] = *reinterpret_cast<const float4*>(b1 + ch * 128 + cb0 + nt * 16 + lgrp * 4);
#pragma unroll
        for (int tt = 0; tt < 4; ++tt) {
            short8 xf[4];
#pragma unroll
            for (int kk = 0; kk < 4; ++kk)
                xf[kk] = ldsA(bufB, tt * 16 + lrow, kk * 32 + lgrp * 8);
#pragma unroll
            for (int nt = 0; nt < 2; ++nt) {
                f32x4 d = {0.f, 0.f, 0.f, 0.f};
#pragma unroll
                for (int kk = 0; kk < 4; ++kk)
                    d = __builtin_amdgcn_mfma_f32_16x16x32_bf16(w1f[ch & 1][nt][kk], xf[kk], d, 0, 0, 0);
                short4v pk;
                pk[0] = bfbits(gelu_fast(d[0] + b1v[nt].x)); pk[1] = bfbits(gelu_fast(d[1] + b1v[nt].y));
                pk[2] = bfbits(gelu_fast(d[2] + b1v[nt].z)); pk[3] = bfbits(gelu_fast(d[3] + b1v[nt].w));
                int row = tt * 16 + lrow;
                int c = cb0 + nt * 16 + lgrp * 4;
                *reinterpret_cast<short4v*>(&UB[row * 128 + (c ^ ((row & 7) << 3))]) = pk;
            }
        }
        if (ch < 3) {
#pragma unroll
            for (int nt = 0; nt < 2; ++nt)
#pragma unroll
                for (int kk = 0; kk < 4; ++kk)
                    w1f[(ch + 1) & 1][nt][kk] =
                        gld8(w1t + (size_t)((ch + 1) * 128 + cb0 + nt * 16 + lrow) * 128 + kk * 32 + lgrp * 8);
        }
        bar_lds();
#pragma unroll
        for (int tt = 0; tt < 4; ++tt) {
            short8 uf[4];
#pragma unroll
            for (int kk = 0; kk < 4; ++kk)
                uf[kk] = ldsA(UB, tt * 16 + lrow, kk * 32 + lgrp * 8);
#pragma unroll
            for (int nt = 0; nt < 2; ++nt)
#pragma unroll
                for (int kk = 0; kk < 4; ++kk)
                    acc2[nt][tt] = __builtin_amdgcn_mfma_f32_16x16x32_bf16(
                        w2f[nt][kk], uf[kk], acc2[nt][tt], 0, 0, 0);
        }
    }

    if (MODE == 0) {
#pragma unroll
        for (int nt = 0; nt < 2; ++nt) {
            const int n0 = cb0 + nt * 16 + lgrp * 4;
            float4 b2v = *reinterpret_cast<const float4*>(b2 + n0);
#pragma unroll
            for (int tt = 0; tt < 4; ++tt) {
                int tok = base + OFFSET + tt * 16 + lrow; if (tok >= NPIX) tok -= NPIX;
                float4 ov;
                ov.x = hres[nt][tt][0] + b2v.x + acc2[nt][tt][0];
                ov.y = hres[nt][tt][1] + b2v.y + acc2[nt][tt][1];
                ov.z = hres[nt][tt][2] + b2v.z + acc2[nt][tt][2];
                ov.w = hres[nt][tt][3] + b2v.w + acc2[nt][tt][3];
                *reinterpret_cast<float4*>(h + (size_t)tok * 128 + n0) = ov;
            }
        }
    } else {
        short8 wff[4];
#pragma unroll
        for (int kk = 0; kk < 4; ++kk)
            wff[kk] = gld8(wf2t + (size_t)(wid * 16 + lrow) * 128 + kk * 32 + lgrp * 8);
        float4 xv[4];
#pragma unroll
        for (int tt = 0; tt < 4; ++tt) {
            int tok = base + OFFSET + tt * 16 + lrow; if (tok >= NPIX) tok -= NPIX;
            xv[tt] = *reinterpret_cast<const float4*>(x + (size_t)tok * 64 + wid * 16 + lgrp * 4);
        }
        bar_lds();   // mlp2 u-reads done before bufB overwrite
#pragma unroll
        for (int nt = 0; nt < 2; ++nt) {
            const int n0 = cb0 + nt * 16 + lgrp * 4;
            float4 b2v = *reinterpret_cast<const float4*>(b2 + n0);
#pragma unroll
            for (int tt = 0; tt < 4; ++tt) {
                short4v pk;
                pk[0] = bfbits(hres[nt][tt][0] + b2v.x + acc2[nt][tt][0]);
                pk[1] = bfbits(hres[nt][tt][1] + b2v.y + acc2[nt][tt][1]);
                pk[2] = bfbits(hres[nt][tt][2] + b2v.z + acc2[nt][tt][2]);
                pk[3] = bfbits(hres[nt][tt][3] + b2v.w + acc2[nt][tt][3]);
                int row = tt * 16 + lrow;
                int c = cb0 + nt * 16 + lgrp * 4;
                *reinterpret_cast<short4v*>(&bufB[row * 128 + (c ^ ((row & 7) << 3))]) = pk;
            }
        }
        bar_lds();
        float4 bfv = *reinterpret_cast<const float4*>(bf2 + wid * 16 + lgrp * 4);
#pragma unroll
        for (int tt = 0; tt < 4; ++tt) {
            short8 bfr[4];
#pragma unroll
            for (int kk = 0; kk < 4; ++kk)
                bfr[kk] = ldsA(bufB, tt * 16 + lrow, kk * 32 + lgrp * 8);
            f32x4 d = {0.f, 0.f, 0.f, 0.f};
#pragma unroll
            for (int kk = 0; kk < 4; ++kk)
                d = __builtin_amdgcn_mfma_f32_16x16x32_bf16(wff[kk], bfr[kk], d, 0, 0, 0);
            int tok = base + OFFSET + tt * 16 + lrow; if (tok >= NPIX) tok -= NPIX;
            float4 ov;
            ov.x = xv[tt].x + bfv.x + d[0]; ov.y = xv[tt].y + bfv.y + d[1];
            ov.z = xv[tt].z + bfv.z + d[2]; ov.w = xv[tt].w + bfv.w + d[3];
            *reinterpret_cast<float4*>(out + (size_t)tok * 64 + wid * 16 + lgrp * 4) = ov;
        }
    }
}

extern "C" void kernel_launch(void* const* d_in, const int* in_sizes, int n_in,
                              void* d_out, int out_size, void* d_ws, size_t ws_size,
                              hipStream_t stream) {
    (void)in_sizes; (void)n_in; (void)out_size; (void)ws_size;
    const float* x      = (const float*)d_in[0];
    const float* w_ff1  = (const float*)d_in[1];
    const float* b_ff1  = (const float*)d_in[2];
    const float* ln1_g  = (const float*)d_in[3];
    const float* ln1_b  = (const float*)d_in[4];
    const float* w_qkv  = (const float*)d_in[5];
    const float* b_qkv  = (const float*)d_in[6];
    const float* w_proj = (const float*)d_in[7];
    const float* b_proj = (const float*)d_in[8];
    const float* ln2_g  = (const float*)d_in[9];
    const float* ln2_b  = (const float*)d_in[10];
    const float* w_mlp1 = (const float*)d_in[11];
    const float* b_mlp1 = (const float*)d_in[12];
    const float* w_mlp2 = (const float*)d_in[13];
    const float* b_mlp2 = (const float*)d_in[14];
    const float* w_ff2  = (const float*)d_in[15];
    const float* b_ff2  = (const float*)d_in[16];
    float* out = (float*)d_out;

    float* h = (float*)d_ws;                                   // [NPIX,128] fp32
    bf16* wbf = (bf16*)((char*)d_ws + (size_t)NPIX * 128 * 4);
    bf16* ff1t  = wbf;            // [128][64]
    bf16* qkvt  = wbf + 8192;     // 2x[384][128]
    bf16* projt = wbf + 106496;   // 2x[128][128]
    bf16* mlp1t = wbf + 139264;   // 2x[512][128]
    bf16* mlp2t = wbf + 270336;   // 2x[128][512]
    bf16* ff2t  = wbf + 401408;   // [64][128]

    k_convert<<<1600, dim3(256), 0, stream>>>(w_ff1, w_qkv, w_proj, w_mlp1, w_mlp2, w_ff2, wbf);

    const int NB = NPIX / 64;  // 3072
    k_block<0, 0><<<NB, dim3(256), 0, stream>>>(x, h,
        ff1t, b_ff1,
        ln1_g, ln1_b, qkvt, b_qkv, projt, b_proj,
        ln2_g, ln2_b, mlp1t, b_mlp1, mlp2t, b_mlp2,
        ff2t, b_ff2, out);

    k_block<8, 1><<<NB, dim3(256), 0, stream>>>(x, h,
        ff1t, b_ff1,
        ln1_g + 128, ln1_b + 128, qkvt + 49152, b_qkv + 384, projt + 16384, b_proj + 128,
        ln2_g + 128, ln2_b + 128, mlp1t + 65536, b_mlp1 + 512, mlp2t + 65536, b_mlp2 + 128,
        ff2t, b_ff2, out);
}